// Round 10
// baseline (21.348 us; speedup 1.0000x reference)
//
#include <hip/hip_runtime.h>
#include <math.h>

#define HH 1024
#define WW 1024
#define NB 8
#define ROWS 4                       // output rows per block (full 1024-wide band)
#define CHUNKS (HH / ROWS)           // 256
#define NBLK (NB * CHUNKS)           // 2048 blocks; 4 waves = 4 horizontal stripes

// partials layout: ws[bid*8 + k], k = {Sp0, SLp0, Sp1, SLp1, N, NL, 0, 0}
__global__ __launch_bounds__(256, 8) void ul_main(const float* __restrict__ pred,
                                                  const float* __restrict__ target,
                                                  float* __restrict__ partials) {
    const int wv   = threadIdx.x >> 6;     // stripe 0..3
    const int lane = threadIdx.x & 63;
    const int b     = blockIdx.x >> 8;     // batch
    const int chunk = blockIdx.x & 255;
    const int r0    = chunk * ROWS;
    const int col4  = wv * 256 + lane * 4;

    const float* __restrict__ t1p = target + (size_t)(2 * b + 1) * (HH * WW);
    const float* __restrict__ p0p = pred   + (size_t)(2 * b)     * (HH * WW);
    const float* __restrict__ p1p = p0p + (size_t)(HH * WW);

    // ---- phase 1: ALL label loads (6 independent float4, nothing else) ----
    float4 vm[ROWS + 2];
    #pragma unroll
    for (int i = 0; i < ROWS + 2; ++i) {
        int h = r0 - 1 + i;
        h = h < 0 ? 0 : (h >= HH ? HH - 1 : h);
        vm[i] = *(const float4*)(t1p + (size_t)h * WW + col4);
    }

    // ---- phase 2: pack nibbles; neighbor bits via 2 shuffles of packed words ----
    unsigned ppack = 0, myL = 0, myR = 0;
    #pragma unroll
    for (int i = 0; i < ROWS + 2; ++i) {
        const unsigned p = (vm[i].x > 0.5f ? 1u : 0u) | (vm[i].y > 0.5f ? 2u : 0u) |
                           (vm[i].z > 0.5f ? 4u : 0u) | (vm[i].w > 0.5f ? 8u : 0u);
        ppack |= p << (4 * i);
        myL   |= (p & 1u) << i;
        myR   |= ((p >> 3) & 1u) << i;
    }
    const unsigned plpack = __shfl_up(myR, 1);     // left neighbor's col3 bits
    const unsigned prpack = __shfl_down(myL, 1);   // right neighbor's col0 bits

    // ---- in-block halo exchange across the 4 stripes of this row band ----
    __shared__ unsigned eL[4], eR[4];
    const unsigned lbm = __shfl(myL, 0);
    const unsigned rbm = __shfl(myR, 63);
    if (lane == 0) { eL[wv] = lbm; eR[wv] = rbm; }
    __syncthreads();
    const unsigned Lh = (wv > 0) ? eR[wv - 1] : lbm;   // clamp at image edge
    const unsigned Rh = (wv < 3) ? eL[wv + 1] : rbm;
    const unsigned PL = (lane == 0)  ? Lh : plpack;
    const unsigned PR = (lane == 63) ? Rh : prpack;

    // ---- phase 3a: 6-bit windows -> per-row uniformity nibbles ----
    unsigned w6[ROWS + 2];
    #pragma unroll
    for (int i = 0; i < ROWS + 2; ++i) {
        const unsigned p = (ppack >> (4 * i)) & 0xFu;
        w6[i] = ((PL >> i) & 1u) | (p << 1) | (((PR >> i) & 1u) << 5);
    }
    unsigned unis = 0;
    #pragma unroll
    for (int j = 0; j < ROWS; ++j) {
        const unsigned A = w6[j] & w6[j + 1] & w6[j + 2];
        const unsigned O = w6[j] | w6[j + 1] | w6[j + 2];
        unis |= (((A & (A >> 1) & (A >> 2)) | ~(O | (O >> 1) | (O >> 2))) & 0xFu) << (4 * j);
    }

    // ---- phase 3b: gather (branch bodies only loads; compiler may merge) ----
    float4 x0[ROWS], x1[ROWS];
    #pragma unroll
    for (int j = 0; j < ROWS; ++j) {
        if ((unis >> (4 * j)) & 0xFu) {
            const size_t off = (size_t)(r0 + j) * WW + col4;
            x0[j] = *(const float4*)(p0p + off);
            x1[j] = *(const float4*)(p1p + off);
        }
    }

    // ---- phase 3c: consume (fast hardware exp) ----
    float s_p0 = 0.f, s_lp0 = 0.f, s_p1 = 0.f, s_lp1 = 0.f;
    int nC = 0, nL = 0;
    #pragma unroll
    for (int j = 0; j < ROWS; ++j) {
        const unsigned uni = (unis >> (4 * j)) & 0xFu;
        if (uni) {
            const unsigned lb4 = (ppack >> (4 * (j + 1))) & 0xFu;
            nC += __popc(uni);
            nL += __popc(uni & lb4);
            #define UL_DO_K(K, C0, C1)                                          \
                if ((uni >> K) & 1u) {                                          \
                    float sg0 = 1.0f / (1.0f + __expf(-(C0)));                  \
                    float sg1 = 1.0f / (1.0f + __expf(-(C1)));                  \
                    sg0 = fminf(fmaxf(sg0, 1e-7f), 1.0f - 1e-7f);               \
                    sg1 = fminf(fmaxf(sg1, 1e-7f), 1.0f - 1e-7f);               \
                    s_p0 += sg0; s_p1 += sg1;                                   \
                    if ((lb4 >> K) & 1u) { s_lp0 += sg0; s_lp1 += sg1; }        \
                }
            UL_DO_K(0, x0[j].x, x1[j].x)
            UL_DO_K(1, x0[j].y, x1[j].y)
            UL_DO_K(2, x0[j].z, x1[j].z)
            UL_DO_K(3, x0[j].w, x1[j].w)
            #undef UL_DO_K
        }
    }

    // ---- wave reduce (4 floats + 2 ints) ----
    #pragma unroll
    for (int off = 32; off; off >>= 1) {
        s_p0  += __shfl_xor(s_p0,  off, 64);
        s_lp0 += __shfl_xor(s_lp0, off, 64);
        s_p1  += __shfl_xor(s_p1,  off, 64);
        s_lp1 += __shfl_xor(s_lp1, off, 64);
        nC    += __shfl_xor(nC,    off, 64);
        nL    += __shfl_xor(nL,    off, 64);
    }

    __shared__ float sm[4][6];
    if (lane == 0) {
        sm[wv][0] = s_p0;  sm[wv][1] = s_lp0;
        sm[wv][2] = s_p1;  sm[wv][3] = s_lp1;
        sm[wv][4] = (float)nC; sm[wv][5] = (float)nL;
    }
    __syncthreads();
    if (threadIdx.x < 8) {
        const int k = threadIdx.x;
        const float v = (k < 6) ? (sm[0][k] + sm[1][k] + sm[2][k] + sm[3][k]) : 0.0f;
        partials[(size_t)blockIdx.x * 8 + k] = v;
    }
}

// Stage 2: reduce 2048 x 8 partials (float4, parity classes), compute scalar loss
__global__ __launch_bounds__(256) void ul_final(const float* __restrict__ ws,
                                                float* __restrict__ out) {
    const int t = threadIdx.x, lane = t & 63, wv = t >> 6;
    float a0 = 0.f, a1 = 0.f, a2 = 0.f, a3 = 0.f;
    #pragma unroll
    for (int r = 0; r < 16; ++r) {                // 4096 float4s total
        const float4 v = ((const float4*)ws)[t + 256 * r];
        a0 += v.x; a1 += v.y; a2 += v.z; a3 += v.w;
    }
    // butterfly keeping parity class (even t = {Sp0,SLp0,Sp1,SLp1}, odd t = {N,NL,0,0})
    #pragma unroll
    for (int off = 32; off >= 2; off >>= 1) {
        a0 += __shfl_xor(a0, off, 64); a1 += __shfl_xor(a1, off, 64);
        a2 += __shfl_xor(a2, off, 64); a3 += __shfl_xor(a3, off, 64);
    }
    __shared__ float sm[4][2][4];
    if (lane < 2) {
        sm[wv][lane][0] = a0; sm[wv][lane][1] = a1;
        sm[wv][lane][2] = a2; sm[wv][lane][3] = a3;
    }
    __syncthreads();
    if (t == 0) {
        float Sp0 = 0.f, SLp0 = 0.f, Sp1 = 0.f, SLp1 = 0.f, N = 0.f, NL = 0.f;
        #pragma unroll
        for (int w = 0; w < 4; ++w) {
            Sp0 += sm[w][0][0]; SLp0 += sm[w][0][1];
            Sp1 += sm[w][0][2]; SLp1 += sm[w][0][3];
            N   += sm[w][1][0]; NL   += sm[w][1][1];
        }
        const float tp0 = 0.95f * Sp0 - 0.9f * SLp0;
        const float st0 = 0.95f * N   - 0.9f * NL;
        const float fn0 = st0 - tp0;
        const float fp0 = Sp0 - tp0;
        const float tp1 = 0.05f * Sp1 + 0.9f * SLp1;
        const float st1 = 0.05f * N   + 0.9f * NL;
        const float fn1 = st1 - tp1;
        const float fp1 = Sp1 - tp1;
        const float d0 = (tp0 + 1e-7f) / (tp0 + 0.6f * fn0 + 0.4f * fp0 + 1e-7f);
        const float d1 = (tp1 + 1e-7f) / (tp1 + 0.6f * fn1 + 0.4f * fp1 + 1e-7f);
        const float back = 1.0f - d0;
        const float fore = sqrtf(fmaxf(1.0f - d1, 0.0f));   // (1-d)*(1-d)^-0.5
        out[0] = 0.5f * (back + fore);                       // WEIGHT=1 kills CE term
    }
}

extern "C" void kernel_launch(void* const* d_in, const int* in_sizes, int n_in,
                              void* d_out, int out_size, void* d_ws, size_t ws_size,
                              hipStream_t stream) {
    const float* pred   = (const float*)d_in[0];
    const float* target = (const float*)d_in[1];
    float* partials = (float*)d_ws;    // 2048 * 8 floats = 64 KiB
    float* out      = (float*)d_out;

    ul_main<<<NBLK, 256, 0, stream>>>(pred, target, partials);
    ul_final<<<1, 256, 0, stream>>>(partials, out);
}

// Round 11
// 20.521 us; speedup vs baseline: 1.0403x; 1.0403x over previous
//
#include <hip/hip_runtime.h>
#include <math.h>

#define HH 1024
#define WW 1024
#define NB 8
#define ROWS 8                       // output rows per block (full 1024-wide band)
#define CHUNKS (HH / ROWS)           // 128
#define NBLK (NB * CHUNKS)           // 1024 blocks; 4 waves = 4 horizontal stripes

// partials layout: ws[bid*8 + k], k = {Sp0, SLp0, Sp1, SLp1, N, NL, 0, 0}
__global__ __launch_bounds__(256, 4) void ul_main(const float* __restrict__ pred,
                                                  const float* __restrict__ target,
                                                  float* __restrict__ partials) {
    const int wv   = threadIdx.x >> 6;     // stripe 0..3
    const int lane = threadIdx.x & 63;
    const int b     = blockIdx.x >> 7;     // batch
    const int chunk = blockIdx.x & 127;
    const int r0    = chunk * ROWS;
    const int col4  = wv * 256 + lane * 4;

    const float* __restrict__ t1p = target + (size_t)(2 * b + 1) * (HH * WW);
    const float* __restrict__ p0p = pred   + (size_t)(2 * b)     * (HH * WW);
    const float* __restrict__ p1p = p0p + (size_t)(HH * WW);

    // ---- phase 1: ALL label loads (10 independent float4, nothing else) ----
    float4 vm[ROWS + 2];
    #pragma unroll
    for (int i = 0; i < ROWS + 2; ++i) {
        int h = r0 - 1 + i;
        h = h < 0 ? 0 : (h >= HH ? HH - 1 : h);
        vm[i] = *(const float4*)(t1p + (size_t)h * WW + col4);
    }

    // ---- phase 2: pack nibbles; neighbor bits via 2 shuffles of packed words ----
    unsigned long long ppack = 0;
    unsigned myL = 0, myR = 0;
    #pragma unroll
    for (int i = 0; i < ROWS + 2; ++i) {
        const unsigned p = (vm[i].x > 0.5f ? 1u : 0u) | (vm[i].y > 0.5f ? 2u : 0u) |
                           (vm[i].z > 0.5f ? 4u : 0u) | (vm[i].w > 0.5f ? 8u : 0u);
        ppack |= (unsigned long long)p << (4 * i);
        myL   |= (p & 1u) << i;
        myR   |= ((p >> 3) & 1u) << i;
    }
    const unsigned plpack = __shfl_up(myR, 1);     // left neighbor's col3 bits
    const unsigned prpack = __shfl_down(myL, 1);   // right neighbor's col0 bits

    // ---- in-block halo exchange across the 4 stripes of this row band ----
    __shared__ unsigned eL[4], eR[4];
    const unsigned lbm = __shfl(myL, 0);
    const unsigned rbm = __shfl(myR, 63);
    if (lane == 0) { eL[wv] = lbm; eR[wv] = rbm; }
    __syncthreads();
    const unsigned Lh = (wv > 0) ? eR[wv - 1] : lbm;   // clamp at image edge
    const unsigned Rh = (wv < 3) ? eL[wv + 1] : rbm;
    const unsigned PL = (lane == 0)  ? Lh : plpack;
    const unsigned PR = (lane == 63) ? Rh : prpack;

    // ---- phase 3a: 6-bit windows -> per-row uniformity nibbles ----
    unsigned w6[ROWS + 2];
    #pragma unroll
    for (int i = 0; i < ROWS + 2; ++i) {
        const unsigned p = (unsigned)(ppack >> (4 * i)) & 0xFu;
        w6[i] = ((PL >> i) & 1u) | (p << 1) | (((PR >> i) & 1u) << 5);
    }
    unsigned unis = 0;
    #pragma unroll
    for (int j = 0; j < ROWS; ++j) {
        const unsigned A = w6[j] & w6[j + 1] & w6[j + 2];
        const unsigned O = w6[j] | w6[j + 1] | w6[j + 2];
        unis |= (((A & (A >> 1) & (A >> 2)) | ~(O | (O >> 1) | (O >> 2))) & 0xFu) << (4 * j);
    }

    // ---- phase 3b: merged gather+consume (execz skips empty rows entirely;
    //      proven equivalent-or-better than the explicit split: R9 null) ----
    float s_p0 = 0.f, s_lp0 = 0.f, s_p1 = 0.f, s_lp1 = 0.f;
    int nCL = 0;                               // nC in low 16 bits, nL in high 16
    #pragma unroll
    for (int j = 0; j < ROWS; ++j) {
        const unsigned uni = (unis >> (4 * j)) & 0xFu;
        if (uni) {
            const size_t off = (size_t)(r0 + j) * WW + col4;
            const float4 x0 = *(const float4*)(p0p + off);
            const float4 x1 = *(const float4*)(p1p + off);
            const unsigned lb4 = (unsigned)(ppack >> (4 * (j + 1))) & 0xFu;
            nCL += __popc(uni) + (__popc(uni & lb4) << 16);
            #define UL_DO_K(K, C0, C1)                                          \
                if ((uni >> K) & 1u) {                                          \
                    float sg0 = 1.0f / (1.0f + __expf(-(C0)));                  \
                    float sg1 = 1.0f / (1.0f + __expf(-(C1)));                  \
                    sg0 = fminf(fmaxf(sg0, 1e-7f), 1.0f - 1e-7f);               \
                    sg1 = fminf(fmaxf(sg1, 1e-7f), 1.0f - 1e-7f);               \
                    s_p0 += sg0; s_p1 += sg1;                                   \
                    if ((lb4 >> K) & 1u) { s_lp0 += sg0; s_lp1 += sg1; }        \
                }
            UL_DO_K(0, x0.x, x1.x)
            UL_DO_K(1, x0.y, x1.y)
            UL_DO_K(2, x0.z, x1.z)
            UL_DO_K(3, x0.w, x1.w)
            #undef UL_DO_K
        }
    }

    // ---- wave reduce (4 floats + 1 packed int) ----
    #pragma unroll
    for (int off = 32; off; off >>= 1) {
        s_p0  += __shfl_xor(s_p0,  off, 64);
        s_lp0 += __shfl_xor(s_lp0, off, 64);
        s_p1  += __shfl_xor(s_p1,  off, 64);
        s_lp1 += __shfl_xor(s_lp1, off, 64);
        nCL   += __shfl_xor(nCL,   off, 64);
    }

    __shared__ float sm[4][6];
    if (lane == 0) {
        sm[wv][0] = s_p0;  sm[wv][1] = s_lp0;
        sm[wv][2] = s_p1;  sm[wv][3] = s_lp1;
        sm[wv][4] = (float)(nCL & 0xFFFF);       // nC (wave sum <= 2048, no overflow)
        sm[wv][5] = (float)(nCL >> 16);          // nL
    }
    __syncthreads();
    if (threadIdx.x < 8) {
        const int k = threadIdx.x;
        const float v = (k < 6) ? (sm[0][k] + sm[1][k] + sm[2][k] + sm[3][k]) : 0.0f;
        partials[(size_t)blockIdx.x * 8 + k] = v;
    }
}

// Stage 2: reduce 1024 x 8 partials (float4, parity classes), compute scalar loss
__global__ __launch_bounds__(256) void ul_final(const float* __restrict__ ws,
                                                float* __restrict__ out) {
    const int t = threadIdx.x, lane = t & 63, wv = t >> 6;
    float a0 = 0.f, a1 = 0.f, a2 = 0.f, a3 = 0.f;
    #pragma unroll
    for (int r = 0; r < 8; ++r) {                 // 2048 float4s total
        const float4 v = ((const float4*)ws)[t + 256 * r];
        a0 += v.x; a1 += v.y; a2 += v.z; a3 += v.w;
    }
    // butterfly keeping parity class (even t = {Sp0,SLp0,Sp1,SLp1}, odd t = {N,NL,0,0})
    #pragma unroll
    for (int off = 32; off >= 2; off >>= 1) {
        a0 += __shfl_xor(a0, off, 64); a1 += __shfl_xor(a1, off, 64);
        a2 += __shfl_xor(a2, off, 64); a3 += __shfl_xor(a3, off, 64);
    }
    __shared__ float sm[4][2][4];
    if (lane < 2) {
        sm[wv][lane][0] = a0; sm[wv][lane][1] = a1;
        sm[wv][lane][2] = a2; sm[wv][lane][3] = a3;
    }
    __syncthreads();
    if (t == 0) {
        float Sp0 = 0.f, SLp0 = 0.f, Sp1 = 0.f, SLp1 = 0.f, N = 0.f, NL = 0.f;
        #pragma unroll
        for (int w = 0; w < 4; ++w) {
            Sp0 += sm[w][0][0]; SLp0 += sm[w][0][1];
            Sp1 += sm[w][0][2]; SLp1 += sm[w][0][3];
            N   += sm[w][1][0]; NL   += sm[w][1][1];
        }
        const float tp0 = 0.95f * Sp0 - 0.9f * SLp0;
        const float st0 = 0.95f * N   - 0.9f * NL;
        const float fn0 = st0 - tp0;
        const float fp0 = Sp0 - tp0;
        const float tp1 = 0.05f * Sp1 + 0.9f * SLp1;
        const float st1 = 0.05f * N   + 0.9f * NL;
        const float fn1 = st1 - tp1;
        const float fp1 = Sp1 - tp1;
        const float d0 = (tp0 + 1e-7f) / (tp0 + 0.6f * fn0 + 0.4f * fp0 + 1e-7f);
        const float d1 = (tp1 + 1e-7f) / (tp1 + 0.6f * fn1 + 0.4f * fp1 + 1e-7f);
        const float back = 1.0f - d0;
        const float fore = sqrtf(fmaxf(1.0f - d1, 0.0f));   // (1-d)*(1-d)^-0.5
        out[0] = 0.5f * (back + fore);                       // WEIGHT=1 kills CE term
    }
}

extern "C" void kernel_launch(void* const* d_in, const int* in_sizes, int n_in,
                              void* d_out, int out_size, void* d_ws, size_t ws_size,
                              hipStream_t stream) {
    const float* pred   = (const float*)d_in[0];
    const float* target = (const float*)d_in[1];
    float* partials = (float*)d_ws;    // 1024 * 8 floats = 32 KiB
    float* out      = (float*)d_out;

    ul_main<<<NBLK, 256, 0, stream>>>(pred, target, partials);
    ul_final<<<1, 256, 0, stream>>>(partials, out);
}